// Round 4
// baseline (106.608 us; speedup 1.0000x reference)
//
#include <hip/hip_runtime.h>

#define D 128
#define EPS 1e-5f

// k0: zero wsum[nNodes] + btw[128]
__global__ __launch_bounds__(256) void zero_kernel(
    float4* __restrict__ p, int n4)
{
    const int i = blockIdx.x * blockDim.x + threadIdx.x;
    const int stride = gridDim.x * blockDim.x;
    const float4 z = {0.f, 0.f, 0.f, 0.f};
    for (int k = i; k < n4; k += stride) p[k] = z;
}

// k1: wsum[n] = sum of weight over edges whose dst == n
__global__ __launch_bounds__(256) void wsum_kernel(
    const float* __restrict__ weight,
    const int* __restrict__ eidx,
    float* __restrict__ wsum,   // [nNodes], pre-zeroed
    int nEdges)
{
    const int e = blockIdx.x * blockDim.x + threadIdx.x;
    if (e < nEdges) {
        const int2 p = reinterpret_cast<const int2*>(eidx)[e];
        unsafeAtomicAdd(&wsum[p.y], weight[e]);
    }
}

// k2: btw[d] = sum_n wsum[n] * embed[n, d]  (dense scan, 2-way unrolled)
__global__ __launch_bounds__(256) void btw_kernel(
    const float* __restrict__ embed,
    const float* __restrict__ wsum,
    float* __restrict__ btw,    // [128], pre-zeroed
    int nNodes)
{
    __shared__ float sbtw[D];
    const int tid = threadIdx.x;
    for (int i = tid; i < D; i += 256) sbtw[i] = 0.f;
    __syncthreads();

    const int j = tid & 31;                       // lane -> dims 4j..4j+3
    const int hw  = blockIdx.x * 8 + (tid >> 5);
    const int nhw = gridDim.x * 8;

    float4 a0 = {0.f, 0.f, 0.f, 0.f};
    float4 a1 = {0.f, 0.f, 0.f, 0.f};
    int n = hw;
    for (; n + nhw < nNodes; n += 2 * nhw) {
        const float w0 = wsum[n];
        const float w1 = wsum[n + nhw];
        const float4 v0 = reinterpret_cast<const float4*>(embed + (size_t)n * D)[j];
        const float4 v1 = reinterpret_cast<const float4*>(embed + (size_t)(n + nhw) * D)[j];
        a0.x += w0 * v0.x; a0.y += w0 * v0.y; a0.z += w0 * v0.z; a0.w += w0 * v0.w;
        a1.x += w1 * v1.x; a1.y += w1 * v1.y; a1.z += w1 * v1.z; a1.w += w1 * v1.w;
    }
    if (n < nNodes) {
        const float w0 = wsum[n];
        const float4 v0 = reinterpret_cast<const float4*>(embed + (size_t)n * D)[j];
        a0.x += w0 * v0.x; a0.y += w0 * v0.y; a0.z += w0 * v0.z; a0.w += w0 * v0.w;
    }
    a0.x += a1.x; a0.y += a1.y; a0.z += a1.z; a0.w += a1.w;

    atomicAdd(&sbtw[4 * j + 0], a0.x);
    atomicAdd(&sbtw[4 * j + 1], a0.y);
    atomicAdd(&sbtw[4 * j + 2], a0.z);
    atomicAdd(&sbtw[4 * j + 3], a0.w);
    __syncthreads();
    if (tid < D) unsafeAtomicAdd(&btw[tid], sbtw[tid]);
}

// k3: snode[n] = dot(embed[n,:], btw)  (dense scan, 2 rows in flight)
__global__ __launch_bounds__(256) void snode_kernel(
    const float* __restrict__ embed,
    const float* __restrict__ btw,
    float* __restrict__ snode,  // [nNodes]
    int nNodes)
{
    const int tid = threadIdx.x;
    const int j = tid & 31;
    const float4 bt = reinterpret_cast<const float4*>(btw)[j];
    const int hw  = blockIdx.x * 8 + (tid >> 5);
    const int nhw = gridDim.x * 8;

    int n = hw;
    for (; n + nhw < nNodes; n += 2 * nhw) {
        const float4 v0 = reinterpret_cast<const float4*>(embed + (size_t)n * D)[j];
        const float4 v1 = reinterpret_cast<const float4*>(embed + (size_t)(n + nhw) * D)[j];
        float s0 = v0.x * bt.x + v0.y * bt.y + v0.z * bt.z + v0.w * bt.w;
        float s1 = v1.x * bt.x + v1.y * bt.y + v1.z * bt.z + v1.w * bt.w;
        #pragma unroll
        for (int m = 1; m < 32; m <<= 1) {
            s0 += __shfl_xor(s0, m, 64);
            s1 += __shfl_xor(s1, m, 64);
        }
        if (j == 0) {
            snode[n] = s0;
            snode[n + nhw] = s1;
        }
    }
    if (n < nNodes) {
        const float4 v0 = reinterpret_cast<const float4*>(embed + (size_t)n * D)[j];
        float s0 = v0.x * bt.x + v0.y * bt.y + v0.z * bt.z + v0.w * bt.w;
        #pragma unroll
        for (int m = 1; m < 32; m <<= 1)
            s0 += __shfl_xor(s0, m, 64);
        if (j == 0) snode[n] = s0;
    }
}

// k4: out[e] = sigmoid(log(snode[src_e]) + EPS)
__global__ __launch_bounds__(256) void out_kernel(
    const int* __restrict__ eidx,
    const float* __restrict__ snode,
    float* __restrict__ out,
    int nEdges)
{
    const int e = blockIdx.x * blockDim.x + threadIdx.x;
    if (e < nEdges) {
        const int2 p = reinterpret_cast<const int2*>(eidx)[e];
        const float x = logf(snode[p.x]) + EPS;
        out[e] = 1.f / (1.f + expf(-x));
    }
}

extern "C" void kernel_launch(void* const* d_in, const int* in_sizes, int n_in,
                              void* d_out, int out_size, void* d_ws, size_t ws_size,
                              hipStream_t stream) {
    const float* embed  = (const float*)d_in[0];
    const float* weight = (const float*)d_in[1];
    const int*   eidx   = (const int*)d_in[2];
    float* out = (float*)d_out;

    const int nEdges = in_sizes[1];          // weight is (E,1)
    const int nNodes = in_sizes[0] / D;      // embed is (N,128)

    float* wsum  = (float*)d_ws;             // [nNodes]
    float* btw   = wsum + nNodes;            // [128]
    float* snode = btw + D;                  // [nNodes]

    const int nZero4 = (nNodes + D + 3) / 4;
    const int eBlocks = (nEdges + 255) / 256;

    zero_kernel <<<512,     256, 0, stream>>>((float4*)d_ws, nZero4);
    wsum_kernel <<<eBlocks, 256, 0, stream>>>(weight, eidx, wsum, nEdges);
    btw_kernel  <<<2048,    256, 0, stream>>>(embed, wsum, btw, nNodes);
    snode_kernel<<<2048,    256, 0, stream>>>(embed, btw, snode, nNodes);
    out_kernel  <<<eBlocks, 256, 0, stream>>>(eidx, snode, out, nEdges);
}

// Round 5
// 71.186 us; speedup vs baseline: 1.4976x; 1.4976x over previous
//
#include <hip/hip_runtime.h>

#define D 128
#define EPS 1e-5f
#define NBLK 2048   // blocks for the two dense scans

// k0: zero wsum[nNodes]
__global__ __launch_bounds__(256) void zero_kernel(
    float4* __restrict__ p, int n4)
{
    const int i = blockIdx.x * blockDim.x + threadIdx.x;
    const int stride = gridDim.x * blockDim.x;
    const float4 z = {0.f, 0.f, 0.f, 0.f};
    for (int k = i; k < n4; k += stride) p[k] = z;
}

// k1: wsum[n] = sum of weight over edges whose dst == n
__global__ __launch_bounds__(256) void wsum_kernel(
    const float* __restrict__ weight,
    const int* __restrict__ eidx,
    float* __restrict__ wsum,   // [nNodes], pre-zeroed
    int nEdges)
{
    const int e = blockIdx.x * blockDim.x + threadIdx.x;
    if (e < nEdges) {
        const int2 p = reinterpret_cast<const int2*>(eidx)[e];
        unsafeAtomicAdd(&wsum[p.y], weight[e]);
    }
}

// k2a: per-block partial column sums -> partialT[d][block]  (NO global atomics)
__global__ __launch_bounds__(256) void btw_partial_kernel(
    const float* __restrict__ embed,
    const float* __restrict__ wsum,
    float* __restrict__ partialT,   // [D][NBLK]
    int nNodes)
{
    __shared__ float sbtw[D];
    const int tid = threadIdx.x;
    for (int i = tid; i < D; i += 256) sbtw[i] = 0.f;
    __syncthreads();

    const int j = tid & 31;                       // lane -> dims 4j..4j+3
    const int hw  = blockIdx.x * 8 + (tid >> 5);
    const int nhw = gridDim.x * 8;

    float4 a0 = {0.f, 0.f, 0.f, 0.f};
    float4 a1 = {0.f, 0.f, 0.f, 0.f};
    int n = hw;
    for (; n + nhw < nNodes; n += 2 * nhw) {
        const float w0 = wsum[n];
        const float w1 = wsum[n + nhw];
        const float4 v0 = reinterpret_cast<const float4*>(embed + (size_t)n * D)[j];
        const float4 v1 = reinterpret_cast<const float4*>(embed + (size_t)(n + nhw) * D)[j];
        a0.x += w0 * v0.x; a0.y += w0 * v0.y; a0.z += w0 * v0.z; a0.w += w0 * v0.w;
        a1.x += w1 * v1.x; a1.y += w1 * v1.y; a1.z += w1 * v1.z; a1.w += w1 * v1.w;
    }
    if (n < nNodes) {
        const float w0 = wsum[n];
        const float4 v0 = reinterpret_cast<const float4*>(embed + (size_t)n * D)[j];
        a0.x += w0 * v0.x; a0.y += w0 * v0.y; a0.z += w0 * v0.z; a0.w += w0 * v0.w;
    }
    a0.x += a1.x; a0.y += a1.y; a0.z += a1.z; a0.w += a1.w;

    atomicAdd(&sbtw[4 * j + 0], a0.x);
    atomicAdd(&sbtw[4 * j + 1], a0.y);
    atomicAdd(&sbtw[4 * j + 2], a0.z);
    atomicAdd(&sbtw[4 * j + 3], a0.w);
    __syncthreads();
    if (tid < D) partialT[(size_t)tid * NBLK + blockIdx.x] = sbtw[tid];
}

// k2b: btw[d] = sum_b partialT[d][b]   (one block per dim, coalesced 8KB read)
__global__ __launch_bounds__(256) void btw_reduce_kernel(
    const float* __restrict__ partialT,  // [D][NBLK]
    float* __restrict__ btw)             // [128]
{
    __shared__ float red[256];
    const int d = blockIdx.x;
    const int tid = threadIdx.x;
    float s = 0.f;
    const float* row = partialT + (size_t)d * NBLK;
    #pragma unroll
    for (int k = tid; k < NBLK; k += 256) s += row[k];
    red[tid] = s;
    __syncthreads();
    for (int off = 128; off > 0; off >>= 1) {
        if (tid < off) red[tid] += red[tid + off];
        __syncthreads();
    }
    if (tid == 0) btw[d] = red[0];
}

// k3: snode[n] = dot(embed[n,:], btw)
__global__ __launch_bounds__(256) void snode_kernel(
    const float* __restrict__ embed,
    const float* __restrict__ btw,
    float* __restrict__ snode,  // [nNodes]
    int nNodes)
{
    const int tid = threadIdx.x;
    const int j = tid & 31;
    const float4 bt = reinterpret_cast<const float4*>(btw)[j];
    const int hw  = blockIdx.x * 8 + (tid >> 5);
    const int nhw = gridDim.x * 8;

    int n = hw;
    for (; n + nhw < nNodes; n += 2 * nhw) {
        const float4 v0 = reinterpret_cast<const float4*>(embed + (size_t)n * D)[j];
        const float4 v1 = reinterpret_cast<const float4*>(embed + (size_t)(n + nhw) * D)[j];
        float s0 = v0.x * bt.x + v0.y * bt.y + v0.z * bt.z + v0.w * bt.w;
        float s1 = v1.x * bt.x + v1.y * bt.y + v1.z * bt.z + v1.w * bt.w;
        #pragma unroll
        for (int m = 1; m < 32; m <<= 1) {
            s0 += __shfl_xor(s0, m, 64);
            s1 += __shfl_xor(s1, m, 64);
        }
        if (j == 0) {
            snode[n] = s0;
            snode[n + nhw] = s1;
        }
    }
    if (n < nNodes) {
        const float4 v0 = reinterpret_cast<const float4*>(embed + (size_t)n * D)[j];
        float s0 = v0.x * bt.x + v0.y * bt.y + v0.z * bt.z + v0.w * bt.w;
        #pragma unroll
        for (int m = 1; m < 32; m <<= 1)
            s0 += __shfl_xor(s0, m, 64);
        if (j == 0) snode[n] = s0;
    }
}

// k4: out[e] = sigmoid(log(snode[src_e]) + EPS)
__global__ __launch_bounds__(256) void out_kernel(
    const int* __restrict__ eidx,
    const float* __restrict__ snode,
    float* __restrict__ out,
    int nEdges)
{
    const int e = blockIdx.x * blockDim.x + threadIdx.x;
    if (e < nEdges) {
        const int2 p = reinterpret_cast<const int2*>(eidx)[e];
        const float x = logf(snode[p.x]) + EPS;
        out[e] = 1.f / (1.f + expf(-x));
    }
}

extern "C" void kernel_launch(void* const* d_in, const int* in_sizes, int n_in,
                              void* d_out, int out_size, void* d_ws, size_t ws_size,
                              hipStream_t stream) {
    const float* embed  = (const float*)d_in[0];
    const float* weight = (const float*)d_in[1];
    const int*   eidx   = (const int*)d_in[2];
    float* out = (float*)d_out;

    const int nEdges = in_sizes[1];          // weight is (E,1)
    const int nNodes = in_sizes[0] / D;      // embed is (N,128)

    float* wsum     = (float*)d_ws;          // [nNodes]
    float* btw      = wsum + nNodes;         // [128]
    float* snode    = btw + D;               // [nNodes]
    float* partialT = snode + nNodes;        // [D][NBLK] = 1 MB

    const int nZero4 = (nNodes + 3) / 4;     // only wsum needs zeroing
    const int eBlocks = (nEdges + 255) / 256;

    zero_kernel       <<<512,     256, 0, stream>>>((float4*)d_ws, nZero4);
    wsum_kernel       <<<eBlocks, 256, 0, stream>>>(weight, eidx, wsum, nEdges);
    btw_partial_kernel<<<NBLK,    256, 0, stream>>>(embed, wsum, partialT, nNodes);
    btw_reduce_kernel <<<D,       256, 0, stream>>>(partialT, btw);
    snode_kernel      <<<NBLK,    256, 0, stream>>>(embed, btw, snode, nNodes);
    out_kernel        <<<eBlocks, 256, 0, stream>>>(eidx, snode, out, nEdges);
}